// Round 15
// baseline (155.738 us; speedup 1.0000x reference)
//
#include <hip/hip_runtime.h>
#include <stdint.h>

// PoissonNeuronTransform — bit-exact vs the harness's NUMPY reference (ref=np).
// Validated (absmax 0.0, R11-R14): threefry2x32 partitionable bits, uniform
// bit-trick, branchless fdlibm log1pf, double-reciprocal division, +0.002f,
// sequential f32 cumsum, early exit (monotone RN-fadd), wave-internal
// lane-refill balancing.
// Round 15 (perf only): GLOBAL WORK-STEALING. 16 region counters in d_ws
// (64 B apart); waves grab 32-element chunks on demand. Removes the
// end-game tail (one-generation grid, occupancy decayed to ~47%). Element
// math depends only on flat index o and rates[o]; every element handed out
// exactly once -> output unchanged bit-for-bit.

static constexpr int      kElems   = 256 * 32 * 128;   // 1048576 = 2^20
static constexpr int      kSpikes  = 100;              // NUM_SPIKES
static constexpr int      kBlocks  = 2048;             // x256 thr = 8192 waves
static constexpr uint32_t kRegions = 16;
static constexpr uint32_t kRegionSz = (uint32_t)kElems / kRegions;  // 65536
static constexpr uint32_t kChunk   = 32;

__device__ __forceinline__ uint32_t rotl32(uint32_t v, uint32_t d) {
  return (v << d) | (v >> (32u - d));
}

// threefry2x32 with key (0, 42) — matches jax.random.key(42).
__device__ __forceinline__ void threefry2x32_0_42(uint32_t x0, uint32_t x1,
                                                  uint32_t& o0, uint32_t& o1) {
  const uint32_t ks0 = 0u;
  const uint32_t ks1 = 42u;
  const uint32_t ks2 = 0x1BD11BDAu ^ 0u ^ 42u;
  uint32_t a = x0 + ks0;
  uint32_t b = x1 + ks1;
#define TF_ROUND(r) { a += b; b = rotl32(b, (r)); b ^= a; }
  TF_ROUND(13u) TF_ROUND(15u) TF_ROUND(26u) TF_ROUND(6u)
  a += ks1; b += ks2 + 1u;
  TF_ROUND(17u) TF_ROUND(29u) TF_ROUND(16u) TF_ROUND(24u)
  a += ks2; b += ks0 + 2u;
  TF_ROUND(13u) TF_ROUND(15u) TF_ROUND(26u) TF_ROUND(6u)
  a += ks0; b += ks1 + 3u;
  TF_ROUND(17u) TF_ROUND(29u) TF_ROUND(16u) TF_ROUND(24u)
  a += ks1; b += ks2 + 4u;
  TF_ROUND(13u) TF_ROUND(15u) TF_ROUND(26u) TF_ROUND(6u)
  a += ks2; b += ks0 + 5u;
#undef TF_ROUND
  o0 = a; o1 = b;
}

// Branchless fdlibm s_log1pf for x in (-1, 0] — bit-exact port (see R12).
__device__ __forceinline__ float fdlibm_log1pf_nb(float x) {
#pragma clang fp contract(off)
  const float ln2_hi = __uint_as_float(0x3f317180u);
  const float ln2_lo = __uint_as_float(0x3717f7d1u);
  const float Lp1 = __uint_as_float(0x3F2AAAABu);
  const float Lp2 = __uint_as_float(0x3ECCCCCDu);
  const float Lp3 = __uint_as_float(0x3E924925u);
  const float Lp4 = __uint_as_float(0x3E638E29u);
  const float Lp5 = __uint_as_float(0x3E3A3325u);
  const float Lp6 = __uint_as_float(0x3E1CD04Fu);
  const float Lp7 = __uint_as_float(0x3E178897u);

  uint32_t hx = __float_as_uint(x);
  uint32_t ax = hx & 0x7fffffffu;

  float u = 1.0f + x;
  uint32_t hu = __float_as_uint(u);
  int k = (int)(hu >> 23) - 127;
  float c = x - (u - 1.0f);
  c = c / u;                              // f32 IEEE div
  uint32_t m = hu & 0x007fffffu;
  bool half = (m >= 0x3504f7u);
  int k2 = half ? (k + 1) : k;
  float u2 = __uint_as_float(m | (half ? 0x3f000000u : 0x3f800000u));
  float f2 = u2 - 1.0f;

  bool cond0 = ((int32_t)hx <= (int32_t)0xbe95f61fu);
  float kf = cond0 ? 0.0f : (float)k2;
  float ff = cond0 ? x : f2;
  float cc = cond0 ? 0.0f : c;

  float hfsq = (0.5f * ff) * ff;
  float s = ff / (2.0f + ff);             // f32 IEEE div
  float z = s * s;
  float R = z * (Lp1 + z * (Lp2 + z * (Lp3 + z * (Lp4 +
            z * (Lp5 + z * (Lp6 + z * Lp7))))));
  float lowsum = s * (hfsq + R) + (kf * ln2_lo + cc);
  float res = kf * ln2_hi - ((hfsq - lowsum) - ff);

  float tiny2 = x - (x * x) * 0.5f;
  res = (ax < 0x38000000u) ? ((ax < 0x33800000u) ? x : tiny2) : res;
  return res;
}

__global__ void __launch_bounds__(256) poisson_count_kernel(
    const float* __restrict__ rates, int* __restrict__ out,
    uint32_t* __restrict__ ctrs) {
#pragma clang fp contract(off)
  int wid  = blockIdx.x * 4 + ((int)threadIdx.x >> 6);
  int lane = (int)threadIdx.x & 63;
  uint32_t region = (uint32_t)wid & (kRegions - 1u);
  uint32_t region_start = region * kRegionSz;
  uint32_t* ctr = ctrs + region * 16;      // 64 B apart
  uint64_t lmask_lt = (1ull << lane) - 1ull;

  // wave-uniform pool state
  uint32_t pool_base = 0, pool_cnt = 0;
  bool region_empty = false;

  // per-lane element state
  uint32_t o = 0;
  float run = 0.0f;
  int cnt = 0, s = 0;
  double inv_d = 0.0;
  bool active = false;

  while (true) {
    uint64_t needmask = __ballot(!active);
    if (needmask != 0ull) {                       // wave-uniform
      if (pool_cnt == 0u && !region_empty) {      // wave-uniform
        uint32_t base = 0;
        if (lane == 0) base = atomicAdd(ctr, kChunk);
        base = __builtin_amdgcn_readfirstlane(base);
        if (base >= kRegionSz) {
          region_empty = true;
        } else {
          pool_base = region_start + base;        // kChunk | kRegionSz
          pool_cnt = kChunk;
        }
      }
      if (pool_cnt != 0u) {
        if (!active) {
          uint32_t rank = (uint32_t)__popcll(needmask & lmask_lt);
          if (rank < pool_cnt) {
            o = pool_base + rank;
            float rate = rates[o];
            inv_d = 1.0 / (double)rate;           // CR f64 reciprocal
            run = 0.0f; cnt = 0; s = 0;
            active = true;
          }
        }
        uint32_t nneed = (uint32_t)__popcll(needmask);
        uint32_t handed = (nneed < pool_cnt) ? nneed : pool_cnt;
        pool_base += handed;
        pool_cnt -= handed;
      } else if (region_empty && needmask == ~0ull) {
        break;                                    // no work left anywhere
      }
    }

    if (active) {
      uint32_t j = ((uint32_t)s << 20) + o;       // kElems == 2^20
      uint32_t b1, b2;
      threefry2x32_0_42(0u, j, b1, b2);
      uint32_t bits = b1 ^ b2;
      float uu = __uint_as_float((bits >> 9) | 0x3f800000u) - 1.0f;  // [0, 1)
      float expo = -fdlibm_log1pf_nb(-uu);
      float q = (float)((double)expo * inv_d);    // == expo / rate (IEEE f32)
      float delta = q + 0.002f;
      run = run + delta;                          // sequential f32 cumsum
      cnt += (run < 1.0f) ? 1 : 0;
      s += 1;
      if (!(run < 1.0f) || s == kSpikes) {        // early exit (monotone) / cap
        out[o] = cnt;
        active = false;
      }
    }
  }
}

extern "C" void kernel_launch(void* const* d_in, const int* in_sizes, int n_in,
                              void* d_out, int out_size, void* d_ws, size_t ws_size,
                              hipStream_t stream) {
  const float* rates = (const float*)d_in[0];
  int* out = (int*)d_out;
  (void)in_sizes; (void)n_in; (void)out_size; (void)ws_size;
  hipMemsetAsync(d_ws, 0, kRegions * 16 * sizeof(uint32_t), stream);
  poisson_count_kernel<<<kBlocks, 256, 0, stream>>>(rates, out,
                                                    (uint32_t*)d_ws);
}